// Round 3
// baseline (674.362 us; speedup 1.0000x reference)
//
#include <hip/hip_runtime.h>
#include <hip/hip_bf16.h>

typedef __attribute__((ext_vector_type(8))) short short8;
typedef __attribute__((ext_vector_type(4))) float float4v;
typedef unsigned int uint;

static __device__ __forceinline__ float2 up_bf2(uint v) {
    float2 r;
    r.x = __uint_as_float(v << 16);
    r.y = __uint_as_float(v & 0xffff0000u);
    return r;
}
static __device__ __forceinline__ short f2bf_bits(float x) {
    union { __hip_bfloat16 h; short s; } u;
    u.h = __float2bfloat16(x);
    return u.s;
}

// ---------------- CSR build ----------------

__global__ void k_degree(const int* __restrict__ dst, int* __restrict__ deg, int E) {
    int e = blockIdx.x * blockDim.x + threadIdx.x;
    if (e < E) atomicAdd(&deg[dst[e]], 1);
}

__global__ void k_dinv(const int* __restrict__ deg, float* __restrict__ dinv, int n) {
    int i = blockIdx.x * blockDim.x + threadIdx.x;
    if (i < n) dinv[i] = rsqrtf((float)(deg[i] + 1));  // +1 self-loop; always > 0
}

__global__ void k_scan1(const int* __restrict__ deg, int* __restrict__ incl,
                        int* __restrict__ bsum, int n) {
    __shared__ int s[1024];
    int i = blockIdx.x * 1024 + threadIdx.x;
    int v = (i < n) ? deg[i] : 0;
    s[threadIdx.x] = v;
    __syncthreads();
    for (int off = 1; off < 1024; off <<= 1) {
        int t = (threadIdx.x >= off) ? s[threadIdx.x - off] : 0;
        __syncthreads();
        s[threadIdx.x] += t;
        __syncthreads();
    }
    if (i < n) incl[i] = s[threadIdx.x];
    if (threadIdx.x == 1023) bsum[blockIdx.x] = s[1023];
}

__global__ void k_scan2(int* __restrict__ bsum, int nb) {
    __shared__ int s[1024];
    int tid = threadIdx.x;
    int v = (tid < nb) ? bsum[tid] : 0;
    int orig = v;
    s[tid] = v;
    __syncthreads();
    for (int off = 1; off < 1024; off <<= 1) {
        int t = (tid >= off) ? s[tid - off] : 0;
        __syncthreads();
        s[tid] += t;
        __syncthreads();
    }
    if (tid < nb) bsum[tid] = s[tid] - orig;  // exclusive block offsets
}

__global__ void k_scan3(const int* __restrict__ incl, const int* __restrict__ deg,
                        const int* __restrict__ bofs, int* __restrict__ row_ptr,
                        int* __restrict__ cursor, int n) {
    int i = blockIdx.x * blockDim.x + threadIdx.x;
    if (i >= n) return;
    int ex = bofs[i >> 10] + incl[i] - deg[i];
    row_ptr[i] = ex;
    cursor[i] = ex;
    if (i == n - 1) row_ptr[n] = bofs[i >> 10] + incl[i];
}

// builds packed edge list: ew[pos] = {src, bits(dinv[src])}
__global__ void k_csr(const int* __restrict__ src, const int* __restrict__ dst,
                      const float* __restrict__ dinv,
                      int* __restrict__ cursor, int2* __restrict__ ew, int E) {
    int e = blockIdx.x * blockDim.x + threadIdx.x;
    if (e >= E) return;
    int s = src[e];
    int pos = atomicAdd(&cursor[dst[e]], 1);
    ew[pos] = make_int2(s, __float_as_int(dinv[s]));
}

// ---------------- Layer 1 aggregate: aggx = (D^-1/2 A D^-1/2) x ----------------

__global__ __launch_bounds__(256) void k_agg1(const float* __restrict__ x,
                       const float* __restrict__ dinv,
                       const int* __restrict__ row_ptr, const int2* __restrict__ ew,
                       float* __restrict__ aggx, int n) {
    int node = blockIdx.x * 16 + (threadIdx.x >> 4);
    if (node >= n) return;
    int f = threadIdx.x & 15;
    bool act = f < 9;
    float di = dinv[node];
    float acc = act ? di * x[node * 9 + f] : 0.f;  // self-loop
    int e0 = row_ptr[node], e1 = row_ptr[node + 1];
    int e = e0;
    for (; e + 2 <= e1; e += 2) {
        int2 wA = ew[e], wB = ew[e + 1];
        float xa = act ? x[wA.x * 9 + f] : 0.f;
        float xb = act ? x[wB.x * 9 + f] : 0.f;
        acc += __int_as_float(wA.y) * xa + __int_as_float(wB.y) * xb;
    }
    if (e < e1) {
        int2 wA = ew[e];
        float xa = act ? x[wA.x * 9 + f] : 0.f;
        acc += __int_as_float(wA.y) * xa;
    }
    if (act) aggx[node * 9 + f] = di * acc;
}

// ---------------- W2 transpose -> bf16 ----------------

__global__ void k_w2t(const float* __restrict__ W2, __hip_bfloat16* __restrict__ W2t) {
    int idx = blockIdx.x * blockDim.x + threadIdx.x;  // 512*128
    if (idx >= 512 * 128) return;
    int k = idx >> 7, j = idx & 127;
    W2t[j * 512 + k] = __float2bfloat16(W2[idx]);  // W2t[n][k] = B^T
}

// ---------------- Fused layer1-matmul + layer2 GEMM ----------------
// Block: 64 nodes, 256 threads (4 waves, wave w -> rows 16w..16w+15, all 128 cols).
// Phase 1: aggx tile -> LDS.  Phase 2: each wave computes its 16 h1-rows (fp32 VALU,
// W1 via quad-broadcast L1 loads) directly into MFMA A-frag registers (bf16).
// Phase 3: K-loop over 8 steps of BK=64; W2t tile double-buffered in LDS
// (stride 88 shorts: 16B-aligned b128, 2-way-free banking), MFMA accumulate.
__global__ __launch_bounds__(256, 3) void k_l12(
        const float* __restrict__ aggx, const float* __restrict__ W1,
        const float* __restrict__ b1, const __hip_bfloat16* __restrict__ W2t,
        __hip_bfloat16* __restrict__ t2, int n) {
    __shared__ float axs[64 * 12];
    __shared__ short bs[2][128 * 88];
    int t = threadIdx.x;
    int m0 = blockIdx.x * 64;

    // Phase 1: aggx tile (64 x 9, zero-padded rows >= n)
    for (int i = t; i < 64 * 9; i += 256) {
        int r = i / 9, c = i - r * 9;
        axs[r * 12 + c] = (m0 + r < n) ? aggx[(size_t)(m0 + r) * 9 + c] : 0.f;
    }
    __syncthreads();

    int wid = t >> 6, lane = t & 63;
    int r = lane & 15, quad = lane >> 4;
    int row = (wid << 4) + r;  // local row 0..63

    const float* arow = &axs[row * 12];
    float4 av0 = *(const float4*)arow;
    float4 av1 = *(const float4*)(arow + 4);
    float avv[9] = {av0.x, av0.y, av0.z, av0.w, av1.x, av1.y, av1.z, av1.w, arow[8]};

    // pre-issue B stage-0 global loads (overlap with phase 2 VALU)
    int scol = t >> 1;
    int sko = (t & 1) * 32;
    const __hip_bfloat16* gp0 = W2t + (size_t)scol * 512 + sko;
    short8 g0 = *(const short8*)(gp0 + 0);
    short8 g1 = *(const short8*)(gp0 + 8);
    short8 g2 = *(const short8*)(gp0 + 16);
    short8 g3 = *(const short8*)(gp0 + 24);

    // Phase 2: h1 A-frags. frag kt holds k = kt*32 + quad*8 + j (m89 layout)
    short8 af[16];
#pragma unroll
    for (int kt = 0; kt < 16; ++kt) {
        int kb = kt * 32 + quad * 8;
        float4 bb0 = *(const float4*)(b1 + kb);
        float4 bb1 = *(const float4*)(b1 + kb + 4);
        float a8[8] = {bb0.x, bb0.y, bb0.z, bb0.w, bb1.x, bb1.y, bb1.z, bb1.w};
        const float* wp = W1 + kb;
#pragma unroll
        for (int f = 0; f < 9; ++f) {
            float4 wa = *(const float4*)(wp + f * 512);
            float4 wb = *(const float4*)(wp + f * 512 + 4);
            float av = avv[f];
            a8[0] += av * wa.x; a8[1] += av * wa.y; a8[2] += av * wa.z; a8[3] += av * wa.w;
            a8[4] += av * wb.x; a8[5] += av * wb.y; a8[6] += av * wb.z; a8[7] += av * wb.w;
        }
        short8 o;
#pragma unroll
        for (int j = 0; j < 8; ++j) o[j] = f2bf_bits(fmaxf(a8[j], 0.f));
        af[kt] = o;
    }

    // write stage 0 into LDS buf 0
    {
        short* bd = &bs[0][scol * 88 + sko];
        *(short8*)(bd + 0) = g0; *(short8*)(bd + 8) = g1;
        *(short8*)(bd + 16) = g2; *(short8*)(bd + 24) = g3;
    }

    float4v acc[8];
#pragma unroll
    for (int c = 0; c < 8; ++c) acc[c] = (float4v){0, 0, 0, 0};

    // Phase 3: K-loop, BK=64, double-buffered B
    for (int s = 0; s < 8; ++s) {
        __syncthreads();
        if (s < 7) {
            const __hip_bfloat16* gp = W2t + (size_t)scol * 512 + (s + 1) * 64 + sko;
            g0 = *(const short8*)(gp + 0);
            g1 = *(const short8*)(gp + 8);
            g2 = *(const short8*)(gp + 16);
            g3 = *(const short8*)(gp + 24);
        }
        int buf = s & 1;
#pragma unroll
        for (int ks = 0; ks < 2; ++ks) {
            const short* bbase = &bs[buf][ks * 32 + quad * 8];
            short8 bf[8];
#pragma unroll
            for (int c = 0; c < 8; ++c)
                bf[c] = *(const short8*)(bbase + (r + c * 16) * 88);
            short8 a = af[s * 2 + ks];
#pragma unroll
            for (int c = 0; c < 8; ++c)
                acc[c] = __builtin_amdgcn_mfma_f32_16x16x32_bf16(a, bf[c], acc[c], 0, 0, 0);
        }
        if (s < 7) {
            short* bd = &bs[(s + 1) & 1][scol * 88 + sko];
            *(short8*)(bd + 0) = g0; *(short8*)(bd + 8) = g1;
            *(short8*)(bd + 16) = g2; *(short8*)(bd + 24) = g3;
        }
    }

    // Epilogue: C/D col = lane&15, row = quad*4 + reg
    int gm = m0 + (wid << 4) + quad * 4;
#pragma unroll
    for (int i = 0; i < 4; ++i) {
        int node = gm + i;
        if (node < n) {
            __hip_bfloat16* op = t2 + (size_t)node * 128 + r;
#pragma unroll
            for (int c = 0; c < 8; ++c) op[c * 16] = __float2bfloat16(acc[c][i]);
        }
    }
}

// ---------------- Layer 2 aggregate + fused layer-3 matmul ----------------

__global__ __launch_bounds__(256) void k_agg2(const uint* __restrict__ t2u,
                       const float* __restrict__ dinv,
                       const int* __restrict__ row_ptr, const int2* __restrict__ ew,
                       const float* __restrict__ b2, const float* __restrict__ W3,
                       float2* __restrict__ t3, int n) {
    int node = blockIdx.x * 4 + (threadIdx.x >> 6);
    if (node >= n) return;
    int lane = threadIdx.x & 63;
    float di = dinv[node];
    float2 p = up_bf2(t2u[(size_t)node * 64 + lane]);
    float a0 = di * p.x, a1 = di * p.y;  // self-loop
    int e0 = row_ptr[node], e1 = row_ptr[node + 1];
    int e = e0;
    for (; e + 4 <= e1; e += 4) {
        int2 w0 = ew[e], w1 = ew[e + 1], w2 = ew[e + 2], w3 = ew[e + 3];
        uint r0 = t2u[(size_t)w0.x * 64 + lane];
        uint r1 = t2u[(size_t)w1.x * 64 + lane];
        uint r2 = t2u[(size_t)w2.x * 64 + lane];
        uint r3 = t2u[(size_t)w3.x * 64 + lane];
        float2 q0 = up_bf2(r0), q1 = up_bf2(r1), q2 = up_bf2(r2), q3 = up_bf2(r3);
        a0 += __int_as_float(w0.y) * q0.x + __int_as_float(w1.y) * q1.x
            + __int_as_float(w2.y) * q2.x + __int_as_float(w3.y) * q3.x;
        a1 += __int_as_float(w0.y) * q0.y + __int_as_float(w1.y) * q1.y
            + __int_as_float(w2.y) * q2.y + __int_as_float(w3.y) * q3.y;
    }
    for (; e < e1; ++e) {
        int2 w0 = ew[e];
        float2 q0 = up_bf2(t2u[(size_t)w0.x * 64 + lane]);
        a0 += __int_as_float(w0.y) * q0.x;
        a1 += __int_as_float(w0.y) * q0.y;
    }
    float2 bb = *reinterpret_cast<const float2*>(b2 + 2 * lane);
    float h0 = fmaxf(di * a0 + bb.x, 0.f);
    float h1v = fmaxf(di * a1 + bb.y, 0.f);
    float4 wv = *reinterpret_cast<const float4*>(W3 + 4 * lane);
    float c0 = h0 * wv.x + h1v * wv.z;
    float c1 = h0 * wv.y + h1v * wv.w;
#pragma unroll
    for (int off = 32; off; off >>= 1) {
        c0 += __shfl_xor(c0, off);
        c1 += __shfl_xor(c1, off);
    }
    if (lane == 0) t3[node] = make_float2(c0, c1);
}

// ---------------- Layer 3 aggregate + log_softmax ----------------

__global__ void k_agg3(const float2* __restrict__ t3, const float* __restrict__ dinv,
                       const int* __restrict__ row_ptr, const int2* __restrict__ ew,
                       const float* __restrict__ b3, float2* __restrict__ outv, int n) {
    int node = blockIdx.x * blockDim.x + threadIdx.x;
    if (node >= n) return;
    float di = dinv[node];
    float2 s = t3[node];
    float a0 = di * s.x, a1 = di * s.y;
    int e0 = row_ptr[node], e1 = row_ptr[node + 1];
    int e = e0;
    for (; e + 4 <= e1; e += 4) {
        int2 w0 = ew[e], w1 = ew[e + 1], w2 = ew[e + 2], w3 = ew[e + 3];
        float2 q0 = t3[w0.x], q1 = t3[w1.x], q2 = t3[w2.x], q3 = t3[w3.x];
        a0 += __int_as_float(w0.y) * q0.x + __int_as_float(w1.y) * q1.x
            + __int_as_float(w2.y) * q2.x + __int_as_float(w3.y) * q3.x;
        a1 += __int_as_float(w0.y) * q0.y + __int_as_float(w1.y) * q1.y
            + __int_as_float(w2.y) * q2.y + __int_as_float(w3.y) * q3.y;
    }
    for (; e < e1; ++e) {
        int2 w0 = ew[e];
        float2 q0 = t3[w0.x];
        a0 += __int_as_float(w0.y) * q0.x;
        a1 += __int_as_float(w0.y) * q0.y;
    }
    float z0 = di * a0 + b3[0];
    float z1 = di * a1 + b3[1];
    float m = fmaxf(z0, z1);
    float lse = m + logf(expf(z0 - m) + expf(z1 - m));
    outv[node] = make_float2(z0 - lse, z1 - lse);
}

// ---------------- launch ----------------

extern "C" void kernel_launch(void* const* d_in, const int* in_sizes, int n_in,
                              void* d_out, int out_size, void* d_ws, size_t ws_size,
                              hipStream_t stream) {
    const float* x  = (const float*)d_in[0];
    const float* W1 = (const float*)d_in[1];
    const float* b1 = (const float*)d_in[2];
    const float* W2 = (const float*)d_in[3];
    const float* b2 = (const float*)d_in[4];
    const float* W3 = (const float*)d_in[5];
    const float* b3 = (const float*)d_in[6];
    const int* edges = (const int*)d_in[7];

    int n = in_sizes[0] / 9;
    int E = in_sizes[7] / 2;
    const int* src = edges;
    const int* dst = edges + E;

    char* p = (char*)d_ws;
    auto alloc = [&](size_t bytes) {
        char* q = p;
        p += (bytes + 511) & ~(size_t)511;
        return q;
    };
    int*   deg     = (int*)alloc((size_t)n * 4);
    float* dinv    = (float*)alloc((size_t)n * 4);
    int*   incl    = (int*)alloc((size_t)n * 4);
    int*   bsum    = (int*)alloc(4096);
    int*   row_ptr = (int*)alloc((size_t)(n + 1) * 4);
    int*   cursor  = (int*)alloc((size_t)n * 4);
    int2*  ew      = (int2*)alloc((size_t)E * 8);
    float* aggx    = (float*)alloc((size_t)n * 9 * 4);
    __hip_bfloat16* W2t = (__hip_bfloat16*)alloc(512 * 128 * 2);
    __hip_bfloat16* t2  = (__hip_bfloat16*)alloc((size_t)n * 128 * 2);
    float2* t3 = (float2*)alloc((size_t)n * 8);

    const int B = 256;
    hipMemsetAsync(deg, 0, (size_t)n * 4, stream);
    k_degree<<<(E + B - 1) / B, B, 0, stream>>>(dst, deg, E);
    k_dinv<<<(n + B - 1) / B, B, 0, stream>>>(deg, dinv, n);
    int nb = (n + 1023) / 1024;
    k_scan1<<<nb, 1024, 0, stream>>>(deg, incl, bsum, n);
    k_scan2<<<1, 1024, 0, stream>>>(bsum, nb);
    k_scan3<<<(n + B - 1) / B, B, 0, stream>>>(incl, deg, bsum, row_ptr, cursor, n);
    k_csr<<<(E + B - 1) / B, B, 0, stream>>>(src, dst, dinv, cursor, ew, E);

    k_agg1<<<(n + 15) / 16, B, 0, stream>>>(x, dinv, row_ptr, ew, aggx, n);
    k_w2t<<<(512 * 128 + B - 1) / B, B, 0, stream>>>(W2, W2t);
    k_l12<<<(n + 63) / 64, 256, 0, stream>>>(aggx, W1, b1, W2t, t2, n);
    k_agg2<<<(n + 3) / 4, 256, 0, stream>>>((const uint*)t2, dinv, row_ptr, ew, b2, W3, t3, n);

    k_agg3<<<(n + B - 1) / B, B, 0, stream>>>(t3, dinv, row_ptr, ew, b3, (float2*)d_out, n);
}

// Round 4
// 662.998 us; speedup vs baseline: 1.0171x; 1.0171x over previous
//
#include <hip/hip_runtime.h>
#include <hip/hip_bf16.h>

typedef __attribute__((ext_vector_type(8))) short short8;
typedef __attribute__((ext_vector_type(4))) float float4v;
typedef unsigned int uint;

static __device__ __forceinline__ float2 up_bf2(uint v) {
    float2 r;
    r.x = __uint_as_float(v << 16);
    r.y = __uint_as_float(v & 0xffff0000u);
    return r;
}
static __device__ __forceinline__ short f2bf_bits(float x) {
    union { __hip_bfloat16 h; short s; } u;
    u.h = __float2bfloat16(x);
    return u.s;
}

// ---------------- CSR build ----------------

__global__ void k_degree(const int* __restrict__ dst, int* __restrict__ deg, int E) {
    int e = blockIdx.x * blockDim.x + threadIdx.x;
    if (e < E) atomicAdd(&deg[dst[e]], 1);
}

__global__ void k_dinv(const int* __restrict__ deg, float* __restrict__ dinv, int n) {
    int i = blockIdx.x * blockDim.x + threadIdx.x;
    if (i < n) dinv[i] = rsqrtf((float)(deg[i] + 1));  // +1 self-loop; always > 0
}

__global__ void k_scan1(const int* __restrict__ deg, int* __restrict__ incl,
                        int* __restrict__ bsum, int n) {
    __shared__ int s[1024];
    int i = blockIdx.x * 1024 + threadIdx.x;
    int v = (i < n) ? deg[i] : 0;
    s[threadIdx.x] = v;
    __syncthreads();
    for (int off = 1; off < 1024; off <<= 1) {
        int t = (threadIdx.x >= off) ? s[threadIdx.x - off] : 0;
        __syncthreads();
        s[threadIdx.x] += t;
        __syncthreads();
    }
    if (i < n) incl[i] = s[threadIdx.x];
    if (threadIdx.x == 1023) bsum[blockIdx.x] = s[1023];
}

__global__ void k_scan2(int* __restrict__ bsum, int nb) {
    __shared__ int s[1024];
    int tid = threadIdx.x;
    int v = (tid < nb) ? bsum[tid] : 0;
    int orig = v;
    s[tid] = v;
    __syncthreads();
    for (int off = 1; off < 1024; off <<= 1) {
        int t = (tid >= off) ? s[tid - off] : 0;
        __syncthreads();
        s[tid] += t;
        __syncthreads();
    }
    if (tid < nb) bsum[tid] = s[tid] - orig;  // exclusive block offsets
}

__global__ void k_scan3(const int* __restrict__ incl, const int* __restrict__ deg,
                        const int* __restrict__ bofs, int* __restrict__ row_ptr,
                        int* __restrict__ cursor, int n) {
    int i = blockIdx.x * blockDim.x + threadIdx.x;
    if (i >= n) return;
    int ex = bofs[i >> 10] + incl[i] - deg[i];
    row_ptr[i] = ex;
    cursor[i] = ex;
    if (i == n - 1) row_ptr[n] = bofs[i >> 10] + incl[i];
}

// builds packed edge list: ew[pos] = {src, bits(dinv[src])}
__global__ void k_csr(const int* __restrict__ src, const int* __restrict__ dst,
                      const float* __restrict__ dinv,
                      int* __restrict__ cursor, int2* __restrict__ ew, int E) {
    int e = blockIdx.x * blockDim.x + threadIdx.x;
    if (e >= E) return;
    int s = src[e];
    int pos = atomicAdd(&cursor[dst[e]], 1);
    ew[pos] = make_int2(s, __float_as_int(dinv[s]));
}

// ---------------- Layer 1 aggregate: aggx = (D^-1/2 A D^-1/2) x ----------------

__global__ __launch_bounds__(256) void k_agg1(const float* __restrict__ x,
                       const float* __restrict__ dinv,
                       const int* __restrict__ row_ptr, const int2* __restrict__ ew,
                       float* __restrict__ aggx, int n) {
    int node = blockIdx.x * 16 + (threadIdx.x >> 4);
    if (node >= n) return;
    int f = threadIdx.x & 15;
    bool act = f < 9;
    float di = dinv[node];
    float acc = act ? di * x[node * 9 + f] : 0.f;  // self-loop
    int e0 = row_ptr[node], e1 = row_ptr[node + 1];
    int e = e0;
    for (; e + 2 <= e1; e += 2) {
        int2 wA = ew[e], wB = ew[e + 1];
        float xa = act ? x[wA.x * 9 + f] : 0.f;
        float xb = act ? x[wB.x * 9 + f] : 0.f;
        acc += __int_as_float(wA.y) * xa + __int_as_float(wB.y) * xb;
    }
    if (e < e1) {
        int2 wA = ew[e];
        float xa = act ? x[wA.x * 9 + f] : 0.f;
        acc += __int_as_float(wA.y) * xa;
    }
    if (act) aggx[node * 9 + f] = di * acc;
}

// ---------------- W2 transpose -> bf16 ----------------

__global__ void k_w2t(const float* __restrict__ W2, __hip_bfloat16* __restrict__ W2t) {
    int idx = blockIdx.x * blockDim.x + threadIdx.x;  // 512*128
    if (idx >= 512 * 128) return;
    int k = idx >> 7, j = idx & 127;
    W2t[j * 512 + k] = __float2bfloat16(W2[idx]);  // W2t[n][k] = B^T
}

// ---------------- Fused layer1-matmul + layer2 GEMM ----------------
// Block: 64 nodes, 256 threads (4 waves, wave w -> rows 16w..16w+15, all 128 cols).
// Phase 1: aggx tile -> LDS.  Phase 2: each wave computes its 16 h1-rows (fp32 VALU,
// W1 via quad-broadcast L1 loads) directly into MFMA A-frag registers (bf16).
// Phase 3: K-loop over 8 steps of BK=64; W2t tile double-buffered in LDS
// (stride 88 shorts: 16B-aligned b128), MFMA accumulate.
// launch_bounds(256,2): VGPR cap 256 (need ~170) -- (256,3) spilled 772MB/launch!
__global__ __launch_bounds__(256, 2) void k_l12(
        const float* __restrict__ aggx, const float* __restrict__ W1,
        const float* __restrict__ b1, const __hip_bfloat16* __restrict__ W2t,
        __hip_bfloat16* __restrict__ t2, int n) {
    __shared__ float axs[64 * 12];
    __shared__ short bs[2][128 * 88];
    int t = threadIdx.x;
    int m0 = blockIdx.x * 64;

    // Phase 1: aggx tile (64 x 9, zero-padded rows >= n)
    for (int i = t; i < 64 * 9; i += 256) {
        int r = i / 9, c = i - r * 9;
        axs[r * 12 + c] = (m0 + r < n) ? aggx[(size_t)(m0 + r) * 9 + c] : 0.f;
    }
    __syncthreads();

    int wid = t >> 6, lane = t & 63;
    int r = lane & 15, quad = lane >> 4;
    int row = (wid << 4) + r;  // local row 0..63

    const float* arow = &axs[row * 12];
    float4 av0 = *(const float4*)arow;
    float4 av1 = *(const float4*)(arow + 4);
    float avv[9] = {av0.x, av0.y, av0.z, av0.w, av1.x, av1.y, av1.z, av1.w, arow[8]};

    // pre-issue B stage-0 global loads (overlap with phase 2 VALU)
    int scol = t >> 1;
    int sko = (t & 1) * 32;
    const __hip_bfloat16* gp0 = W2t + (size_t)scol * 512 + sko;
    short8 g0 = *(const short8*)(gp0 + 0);
    short8 g1 = *(const short8*)(gp0 + 8);
    short8 g2 = *(const short8*)(gp0 + 16);
    short8 g3 = *(const short8*)(gp0 + 24);

    // Phase 2: h1 A-frags. frag kt holds k = kt*32 + quad*8 + j (m89 layout)
    short8 af[16];
#pragma unroll
    for (int kt = 0; kt < 16; ++kt) {
        int kb = kt * 32 + quad * 8;
        float4 bb0 = *(const float4*)(b1 + kb);
        float4 bb1 = *(const float4*)(b1 + kb + 4);
        float a8[8] = {bb0.x, bb0.y, bb0.z, bb0.w, bb1.x, bb1.y, bb1.z, bb1.w};
        const float* wp = W1 + kb;
#pragma unroll
        for (int f = 0; f < 9; ++f) {
            float4 wa = *(const float4*)(wp + f * 512);
            float4 wb = *(const float4*)(wp + f * 512 + 4);
            float av = avv[f];
            a8[0] += av * wa.x; a8[1] += av * wa.y; a8[2] += av * wa.z; a8[3] += av * wa.w;
            a8[4] += av * wb.x; a8[5] += av * wb.y; a8[6] += av * wb.z; a8[7] += av * wb.w;
        }
        short8 o;
#pragma unroll
        for (int j = 0; j < 8; ++j) o[j] = f2bf_bits(fmaxf(a8[j], 0.f));
        af[kt] = o;
    }

    // write stage 0 into LDS buf 0
    {
        short* bd = &bs[0][scol * 88 + sko];
        *(short8*)(bd + 0) = g0; *(short8*)(bd + 8) = g1;
        *(short8*)(bd + 16) = g2; *(short8*)(bd + 24) = g3;
    }

    float4v acc[8];
#pragma unroll
    for (int c = 0; c < 8; ++c) acc[c] = (float4v){0, 0, 0, 0};

    // Phase 3: K-loop, BK=64, double-buffered B
    for (int s = 0; s < 8; ++s) {
        __syncthreads();
        if (s < 7) {
            const __hip_bfloat16* gp = W2t + (size_t)scol * 512 + (s + 1) * 64 + sko;
            g0 = *(const short8*)(gp + 0);
            g1 = *(const short8*)(gp + 8);
            g2 = *(const short8*)(gp + 16);
            g3 = *(const short8*)(gp + 24);
        }
        int buf = s & 1;
#pragma unroll
        for (int ks = 0; ks < 2; ++ks) {
            const short* bbase = &bs[buf][ks * 32 + quad * 8];
            short8 bf[8];
#pragma unroll
            for (int c = 0; c < 8; ++c)
                bf[c] = *(const short8*)(bbase + (r + c * 16) * 88);
            short8 a = af[s * 2 + ks];
#pragma unroll
            for (int c = 0; c < 8; ++c)
                acc[c] = __builtin_amdgcn_mfma_f32_16x16x32_bf16(a, bf[c], acc[c], 0, 0, 0);
        }
        if (s < 7) {
            short* bd = &bs[(s + 1) & 1][scol * 88 + sko];
            *(short8*)(bd + 0) = g0; *(short8*)(bd + 8) = g1;
            *(short8*)(bd + 16) = g2; *(short8*)(bd + 24) = g3;
        }
    }

    // Epilogue: C/D col = lane&15, row = quad*4 + reg
    int gm = m0 + (wid << 4) + quad * 4;
#pragma unroll
    for (int i = 0; i < 4; ++i) {
        int node = gm + i;
        if (node < n) {
            __hip_bfloat16* op = t2 + (size_t)node * 128 + r;
#pragma unroll
            for (int c = 0; c < 8; ++c) op[c * 16] = __float2bfloat16(acc[c][i]);
        }
    }
}

// ---------------- Layer 2 aggregate + fused layer-3 matmul ----------------

__global__ __launch_bounds__(256) void k_agg2(const uint* __restrict__ t2u,
                       const float* __restrict__ dinv,
                       const int* __restrict__ row_ptr, const int2* __restrict__ ew,
                       const float* __restrict__ b2, const float* __restrict__ W3,
                       float2* __restrict__ t3, int n) {
    int node = blockIdx.x * 4 + (threadIdx.x >> 6);
    if (node >= n) return;
    int lane = threadIdx.x & 63;
    float di = dinv[node];
    float2 p = up_bf2(t2u[(size_t)node * 64 + lane]);
    float a0 = di * p.x, a1 = di * p.y;  // self-loop
    int e0 = row_ptr[node], e1 = row_ptr[node + 1];
    int e = e0;
    for (; e + 4 <= e1; e += 4) {
        int2 w0 = ew[e], w1 = ew[e + 1], w2 = ew[e + 2], w3 = ew[e + 3];
        uint r0 = t2u[(size_t)w0.x * 64 + lane];
        uint r1 = t2u[(size_t)w1.x * 64 + lane];
        uint r2 = t2u[(size_t)w2.x * 64 + lane];
        uint r3 = t2u[(size_t)w3.x * 64 + lane];
        float2 q0 = up_bf2(r0), q1 = up_bf2(r1), q2 = up_bf2(r2), q3 = up_bf2(r3);
        a0 += __int_as_float(w0.y) * q0.x + __int_as_float(w1.y) * q1.x
            + __int_as_float(w2.y) * q2.x + __int_as_float(w3.y) * q3.x;
        a1 += __int_as_float(w0.y) * q0.y + __int_as_float(w1.y) * q1.y
            + __int_as_float(w2.y) * q2.y + __int_as_float(w3.y) * q3.y;
    }
    for (; e < e1; ++e) {
        int2 w0 = ew[e];
        float2 q0 = up_bf2(t2u[(size_t)w0.x * 64 + lane]);
        a0 += __int_as_float(w0.y) * q0.x;
        a1 += __int_as_float(w0.y) * q0.y;
    }
    float2 bb = *reinterpret_cast<const float2*>(b2 + 2 * lane);
    float h0 = fmaxf(di * a0 + bb.x, 0.f);
    float h1v = fmaxf(di * a1 + bb.y, 0.f);
    float4 wv = *reinterpret_cast<const float4*>(W3 + 4 * lane);
    float c0 = h0 * wv.x + h1v * wv.z;
    float c1 = h0 * wv.y + h1v * wv.w;
#pragma unroll
    for (int off = 32; off; off >>= 1) {
        c0 += __shfl_xor(c0, off);
        c1 += __shfl_xor(c1, off);
    }
    if (lane == 0) t3[node] = make_float2(c0, c1);
}

// ---------------- Layer 3 aggregate + log_softmax ----------------

__global__ void k_agg3(const float2* __restrict__ t3, const float* __restrict__ dinv,
                       const int* __restrict__ row_ptr, const int2* __restrict__ ew,
                       const float* __restrict__ b3, float2* __restrict__ outv, int n) {
    int node = blockIdx.x * blockDim.x + threadIdx.x;
    if (node >= n) return;
    float di = dinv[node];
    float2 s = t3[node];
    float a0 = di * s.x, a1 = di * s.y;
    int e0 = row_ptr[node], e1 = row_ptr[node + 1];
    int e = e0;
    for (; e + 4 <= e1; e += 4) {
        int2 w0 = ew[e], w1 = ew[e + 1], w2 = ew[e + 2], w3 = ew[e + 3];
        float2 q0 = t3[w0.x], q1 = t3[w1.x], q2 = t3[w2.x], q3 = t3[w3.x];
        a0 += __int_as_float(w0.y) * q0.x + __int_as_float(w1.y) * q1.x
            + __int_as_float(w2.y) * q2.x + __int_as_float(w3.y) * q3.x;
        a1 += __int_as_float(w0.y) * q0.y + __int_as_float(w1.y) * q1.y
            + __int_as_float(w2.y) * q2.y + __int_as_float(w3.y) * q3.y;
    }
    for (; e < e1; ++e) {
        int2 w0 = ew[e];
        float2 q0 = t3[w0.x];
        a0 += __int_as_float(w0.y) * q0.x;
        a1 += __int_as_float(w0.y) * q0.y;
    }
    float z0 = di * a0 + b3[0];
    float z1 = di * a1 + b3[1];
    float m = fmaxf(z0, z1);
    float lse = m + logf(expf(z0 - m) + expf(z1 - m));
    outv[node] = make_float2(z0 - lse, z1 - lse);
}

// ---------------- launch ----------------

extern "C" void kernel_launch(void* const* d_in, const int* in_sizes, int n_in,
                              void* d_out, int out_size, void* d_ws, size_t ws_size,
                              hipStream_t stream) {
    const float* x  = (const float*)d_in[0];
    const float* W1 = (const float*)d_in[1];
    const float* b1 = (const float*)d_in[2];
    const float* W2 = (const float*)d_in[3];
    const float* b2 = (const float*)d_in[4];
    const float* W3 = (const float*)d_in[5];
    const float* b3 = (const float*)d_in[6];
    const int* edges = (const int*)d_in[7];

    int n = in_sizes[0] / 9;
    int E = in_sizes[7] / 2;
    const int* src = edges;
    const int* dst = edges + E;

    char* p = (char*)d_ws;
    auto alloc = [&](size_t bytes) {
        char* q = p;
        p += (bytes + 511) & ~(size_t)511;
        return q;
    };
    int*   deg     = (int*)alloc((size_t)n * 4);
    float* dinv    = (float*)alloc((size_t)n * 4);
    int*   incl    = (int*)alloc((size_t)n * 4);
    int*   bsum    = (int*)alloc(4096);
    int*   row_ptr = (int*)alloc((size_t)(n + 1) * 4);
    int*   cursor  = (int*)alloc((size_t)n * 4);
    int2*  ew      = (int2*)alloc((size_t)E * 8);
    float* aggx    = (float*)alloc((size_t)n * 9 * 4);
    __hip_bfloat16* W2t = (__hip_bfloat16*)alloc(512 * 128 * 2);
    __hip_bfloat16* t2  = (__hip_bfloat16*)alloc((size_t)n * 128 * 2);
    float2* t3 = (float2*)alloc((size_t)n * 8);

    const int B = 256;
    hipMemsetAsync(deg, 0, (size_t)n * 4, stream);
    k_degree<<<(E + B - 1) / B, B, 0, stream>>>(dst, deg, E);
    k_dinv<<<(n + B - 1) / B, B, 0, stream>>>(deg, dinv, n);
    int nb = (n + 1023) / 1024;
    k_scan1<<<nb, 1024, 0, stream>>>(deg, incl, bsum, n);
    k_scan2<<<1, 1024, 0, stream>>>(bsum, nb);
    k_scan3<<<(n + B - 1) / B, B, 0, stream>>>(incl, deg, bsum, row_ptr, cursor, n);
    k_csr<<<(E + B - 1) / B, B, 0, stream>>>(src, dst, dinv, cursor, ew, E);

    k_agg1<<<(n + 15) / 16, B, 0, stream>>>(x, dinv, row_ptr, ew, aggx, n);
    k_w2t<<<(512 * 128 + B - 1) / B, B, 0, stream>>>(W2, W2t);
    k_l12<<<(n + 63) / 64, 256, 0, stream>>>(aggx, W1, b1, W2t, t2, n);
    k_agg2<<<(n + 3) / 4, 256, 0, stream>>>((const uint*)t2, dinv, row_ptr, ew, b2, W3, t3, n);

    k_agg3<<<(n + B - 1) / B, B, 0, stream>>>(t3, dinv, row_ptr, ew, b3, (float2*)d_out, n);
}

// Round 5
// 301.673 us; speedup vs baseline: 2.2354x; 2.1977x over previous
//
#include <hip/hip_runtime.h>
#include <hip/hip_bf16.h>

typedef __attribute__((ext_vector_type(8))) short short8;
typedef __attribute__((ext_vector_type(4))) float float4v;
typedef unsigned int uint;

static __device__ __forceinline__ float2 up_bf2(uint v) {
    float2 r;
    r.x = __uint_as_float(v << 16);
    r.y = __uint_as_float(v & 0xffff0000u);
    return r;
}
static __device__ __forceinline__ short f2bf_bits(float x) {
    union { __hip_bfloat16 h; short s; } u;
    u.h = __float2bfloat16(x);
    return u.s;
}

// ---------------- CSR build ----------------

__global__ void k_degree(const int* __restrict__ dst, int* __restrict__ deg, int E) {
    int e = blockIdx.x * blockDim.x + threadIdx.x;
    if (e < E) atomicAdd(&deg[dst[e]], 1);
}

__global__ void k_dinv(const int* __restrict__ deg, float* __restrict__ dinv, int n) {
    int i = blockIdx.x * blockDim.x + threadIdx.x;
    if (i < n) dinv[i] = rsqrtf((float)(deg[i] + 1));  // +1 self-loop; always > 0
}

__global__ void k_scan1(const int* __restrict__ deg, int* __restrict__ incl,
                        int* __restrict__ bsum, int n) {
    __shared__ int s[1024];
    int i = blockIdx.x * 1024 + threadIdx.x;
    int v = (i < n) ? deg[i] : 0;
    s[threadIdx.x] = v;
    __syncthreads();
    for (int off = 1; off < 1024; off <<= 1) {
        int t = (threadIdx.x >= off) ? s[threadIdx.x - off] : 0;
        __syncthreads();
        s[threadIdx.x] += t;
        __syncthreads();
    }
    if (i < n) incl[i] = s[threadIdx.x];
    if (threadIdx.x == 1023) bsum[blockIdx.x] = s[1023];
}

__global__ void k_scan2(int* __restrict__ bsum, int nb) {
    __shared__ int s[1024];
    int tid = threadIdx.x;
    int v = (tid < nb) ? bsum[tid] : 0;
    int orig = v;
    s[tid] = v;
    __syncthreads();
    for (int off = 1; off < 1024; off <<= 1) {
        int t = (tid >= off) ? s[tid - off] : 0;
        __syncthreads();
        s[tid] += t;
        __syncthreads();
    }
    if (tid < nb) bsum[tid] = s[tid] - orig;  // exclusive block offsets
}

__global__ void k_scan3(const int* __restrict__ incl, const int* __restrict__ deg,
                        const int* __restrict__ bofs, int* __restrict__ row_ptr,
                        int* __restrict__ cursor, int n) {
    int i = blockIdx.x * blockDim.x + threadIdx.x;
    if (i >= n) return;
    int ex = bofs[i >> 10] + incl[i] - deg[i];
    row_ptr[i] = ex;
    cursor[i] = ex;
    if (i == n - 1) row_ptr[n] = bofs[i >> 10] + incl[i];
}

// builds packed edge list: ew[pos] = {src, bits(dinv[src])}
__global__ void k_csr(const int* __restrict__ src, const int* __restrict__ dst,
                      const float* __restrict__ dinv,
                      int* __restrict__ cursor, int2* __restrict__ ew, int E) {
    int e = blockIdx.x * blockDim.x + threadIdx.x;
    if (e >= E) return;
    int s = src[e];
    int pos = atomicAdd(&cursor[dst[e]], 1);
    ew[pos] = make_int2(s, __float_as_int(dinv[s]));
}

// ---------------- Layer 1 aggregate: aggx = (D^-1/2 A D^-1/2) x ----------------

__global__ __launch_bounds__(256) void k_agg1(const float* __restrict__ x,
                       const float* __restrict__ dinv,
                       const int* __restrict__ row_ptr, const int2* __restrict__ ew,
                       float* __restrict__ aggx, int n) {
    int node = blockIdx.x * 16 + (threadIdx.x >> 4);
    if (node >= n) return;
    int f = threadIdx.x & 15;
    bool act = f < 9;
    float di = dinv[node];
    float acc = act ? di * x[node * 9 + f] : 0.f;  // self-loop
    int e0 = row_ptr[node], e1 = row_ptr[node + 1];
    int e = e0;
    for (; e + 2 <= e1; e += 2) {
        int2 wA = ew[e], wB = ew[e + 1];
        float xa = act ? x[wA.x * 9 + f] : 0.f;
        float xb = act ? x[wB.x * 9 + f] : 0.f;
        acc += __int_as_float(wA.y) * xa + __int_as_float(wB.y) * xb;
    }
    if (e < e1) {
        int2 wA = ew[e];
        float xa = act ? x[wA.x * 9 + f] : 0.f;
        acc += __int_as_float(wA.y) * xa;
    }
    if (act) aggx[node * 9 + f] = di * acc;
}

// ---------------- W2 transpose -> bf16 ----------------

__global__ void k_w2t(const float* __restrict__ W2, __hip_bfloat16* __restrict__ W2t) {
    int idx = blockIdx.x * blockDim.x + threadIdx.x;  // 512*128
    if (idx >= 512 * 128) return;
    int k = idx >> 7, j = idx & 127;
    W2t[j * 512 + k] = __float2bfloat16(W2[idx]);  // W2t[n][k] = B^T
}

// ---------------- Fused layer1-matmul + layer2 GEMM ----------------
// Block: 64 nodes, 256 threads (4 waves, wave w -> rows 16w..16w+15, all 128 cols).
// A-fragments (h1 rows) are computed JUST-IN-TIME inside the K-loop (2 frags live
// at a time, 8 VGPRs) -- holding all 16 (64 VGPRs) caused arch-VGPR spills
// (702 MB scratch traffic/launch at VGPR_Count=128).
// W2t tile double-buffered in LDS (stride 88 shorts: 16B-aligned b128).
__global__ __launch_bounds__(256, 2) void k_l12(
        const float* __restrict__ aggx, const float* __restrict__ W1,
        const float* __restrict__ b1, const __hip_bfloat16* __restrict__ W2t,
        __hip_bfloat16* __restrict__ t2, int n) {
    __shared__ float axs[64 * 12];
    __shared__ short bs[2][128 * 88];
    int t = threadIdx.x;
    int m0 = blockIdx.x * 64;

    // Phase 1: aggx tile (64 x 9, zero-padded rows >= n)
    for (int i = t; i < 64 * 9; i += 256) {
        int r = i / 9, c = i - r * 9;
        axs[r * 12 + c] = (m0 + r < n) ? aggx[(size_t)(m0 + r) * 9 + c] : 0.f;
    }
    __syncthreads();

    int wid = t >> 6, lane = t & 63;
    int r = lane & 15, quad = lane >> 4;
    int row = (wid << 4) + r;  // local row 0..63

    const float* arow = &axs[row * 12];
    float4 av0 = *(const float4*)arow;
    float4 av1 = *(const float4*)(arow + 4);
    float avv[9] = {av0.x, av0.y, av0.z, av0.w, av1.x, av1.y, av1.z, av1.w, arow[8]};

    // stage-0 B global loads
    int scol = t >> 1;
    int sko = (t & 1) * 32;
    const __hip_bfloat16* gp0 = W2t + (size_t)scol * 512 + sko;
    short8 g0 = *(const short8*)(gp0 + 0);
    short8 g1 = *(const short8*)(gp0 + 8);
    short8 g2 = *(const short8*)(gp0 + 16);
    short8 g3 = *(const short8*)(gp0 + 24);
    {
        short* bd = &bs[0][scol * 88 + sko];
        *(short8*)(bd + 0) = g0; *(short8*)(bd + 8) = g1;
        *(short8*)(bd + 16) = g2; *(short8*)(bd + 24) = g3;
    }

    float4v acc[8];
#pragma unroll
    for (int c = 0; c < 8; ++c) acc[c] = (float4v){0, 0, 0, 0};

    // K-loop, BK=64, double-buffered B; A-frag computed per ks step
    for (int s = 0; s < 8; ++s) {
        __syncthreads();
        if (s < 7) {
            const __hip_bfloat16* gp = W2t + (size_t)scol * 512 + (s + 1) * 64 + sko;
            g0 = *(const short8*)(gp + 0);
            g1 = *(const short8*)(gp + 8);
            g2 = *(const short8*)(gp + 16);
            g3 = *(const short8*)(gp + 24);
        }
        int buf = s & 1;
#pragma unroll
        for (int ks = 0; ks < 2; ++ks) {
            // compute A-frag for kt = s*2+ks: h1[row][kb..kb+7] (m89 A layout)
            int kb = (s * 2 + ks) * 32 + quad * 8;
            float4 bb0 = *(const float4*)(b1 + kb);
            float4 bb1 = *(const float4*)(b1 + kb + 4);
            float a8[8] = {bb0.x, bb0.y, bb0.z, bb0.w, bb1.x, bb1.y, bb1.z, bb1.w};
            const float* wp = W1 + kb;
#pragma unroll
            for (int f = 0; f < 9; ++f) {
                float4 wa = *(const float4*)(wp + f * 512);
                float4 wb = *(const float4*)(wp + f * 512 + 4);
                float av = avv[f];
                a8[0] += av * wa.x; a8[1] += av * wa.y; a8[2] += av * wa.z; a8[3] += av * wa.w;
                a8[4] += av * wb.x; a8[5] += av * wb.y; a8[6] += av * wb.z; a8[7] += av * wb.w;
            }
            short8 a;
#pragma unroll
            for (int j = 0; j < 8; ++j) a[j] = f2bf_bits(fmaxf(a8[j], 0.f));

            const short* bbase = &bs[buf][ks * 32 + quad * 8];
#pragma unroll
            for (int c = 0; c < 8; ++c) {
                short8 bf = *(const short8*)(bbase + (r + c * 16) * 88);
                acc[c] = __builtin_amdgcn_mfma_f32_16x16x32_bf16(a, bf, acc[c], 0, 0, 0);
            }
        }
        if (s < 7) {
            short* bd = &bs[(s + 1) & 1][scol * 88 + sko];
            *(short8*)(bd + 0) = g0; *(short8*)(bd + 8) = g1;
            *(short8*)(bd + 16) = g2; *(short8*)(bd + 24) = g3;
        }
    }

    // Epilogue: C/D col = lane&15, row = quad*4 + reg
    int gm = m0 + (wid << 4) + quad * 4;
#pragma unroll
    for (int i = 0; i < 4; ++i) {
        int node = gm + i;
        if (node < n) {
            __hip_bfloat16* op = t2 + (size_t)node * 128 + r;
#pragma unroll
            for (int c = 0; c < 8; ++c) op[c * 16] = __float2bfloat16(acc[c][i]);
        }
    }
}

// ---------------- Layer 2 aggregate + fused layer-3 matmul ----------------

__global__ __launch_bounds__(256) void k_agg2(const uint* __restrict__ t2u,
                       const float* __restrict__ dinv,
                       const int* __restrict__ row_ptr, const int2* __restrict__ ew,
                       const float* __restrict__ b2, const float* __restrict__ W3,
                       float2* __restrict__ t3, int n) {
    int node = blockIdx.x * 4 + (threadIdx.x >> 6);
    if (node >= n) return;
    int lane = threadIdx.x & 63;
    float di = dinv[node];
    float2 p = up_bf2(t2u[(size_t)node * 64 + lane]);
    float a0 = di * p.x, a1 = di * p.y;  // self-loop
    int e0 = row_ptr[node], e1 = row_ptr[node + 1];
    int e = e0;
    for (; e + 4 <= e1; e += 4) {
        int2 w0 = ew[e], w1 = ew[e + 1], w2 = ew[e + 2], w3 = ew[e + 3];
        uint r0 = t2u[(size_t)w0.x * 64 + lane];
        uint r1 = t2u[(size_t)w1.x * 64 + lane];
        uint r2 = t2u[(size_t)w2.x * 64 + lane];
        uint r3 = t2u[(size_t)w3.x * 64 + lane];
        float2 q0 = up_bf2(r0), q1 = up_bf2(r1), q2 = up_bf2(r2), q3 = up_bf2(r3);
        a0 += __int_as_float(w0.y) * q0.x + __int_as_float(w1.y) * q1.x
            + __int_as_float(w2.y) * q2.x + __int_as_float(w3.y) * q3.x;
        a1 += __int_as_float(w0.y) * q0.y + __int_as_float(w1.y) * q1.y
            + __int_as_float(w2.y) * q2.y + __int_as_float(w3.y) * q3.y;
    }
    for (; e < e1; ++e) {
        int2 w0 = ew[e];
        float2 q0 = up_bf2(t2u[(size_t)w0.x * 64 + lane]);
        a0 += __int_as_float(w0.y) * q0.x;
        a1 += __int_as_float(w0.y) * q0.y;
    }
    float2 bb = *reinterpret_cast<const float2*>(b2 + 2 * lane);
    float h0 = fmaxf(di * a0 + bb.x, 0.f);
    float h1v = fmaxf(di * a1 + bb.y, 0.f);
    float4 wv = *reinterpret_cast<const float4*>(W3 + 4 * lane);
    float c0 = h0 * wv.x + h1v * wv.z;
    float c1 = h0 * wv.y + h1v * wv.w;
#pragma unroll
    for (int off = 32; off; off >>= 1) {
        c0 += __shfl_xor(c0, off);
        c1 += __shfl_xor(c1, off);
    }
    if (lane == 0) t3[node] = make_float2(c0, c1);
}

// ---------------- Layer 3 aggregate + log_softmax ----------------

__global__ void k_agg3(const float2* __restrict__ t3, const float* __restrict__ dinv,
                       const int* __restrict__ row_ptr, const int2* __restrict__ ew,
                       const float* __restrict__ b3, float2* __restrict__ outv, int n) {
    int node = blockIdx.x * blockDim.x + threadIdx.x;
    if (node >= n) return;
    float di = dinv[node];
    float2 s = t3[node];
    float a0 = di * s.x, a1 = di * s.y;
    int e0 = row_ptr[node], e1 = row_ptr[node + 1];
    int e = e0;
    for (; e + 4 <= e1; e += 4) {
        int2 w0 = ew[e], w1 = ew[e + 1], w2 = ew[e + 2], w3 = ew[e + 3];
        float2 q0 = t3[w0.x], q1 = t3[w1.x], q2 = t3[w2.x], q3 = t3[w3.x];
        a0 += __int_as_float(w0.y) * q0.x + __int_as_float(w1.y) * q1.x
            + __int_as_float(w2.y) * q2.x + __int_as_float(w3.y) * q3.x;
        a1 += __int_as_float(w0.y) * q0.y + __int_as_float(w1.y) * q1.y
            + __int_as_float(w2.y) * q2.y + __int_as_float(w3.y) * q3.y;
    }
    for (; e < e1; ++e) {
        int2 w0 = ew[e];
        float2 q0 = t3[w0.x];
        a0 += __int_as_float(w0.y) * q0.x;
        a1 += __int_as_float(w0.y) * q0.y;
    }
    float z0 = di * a0 + b3[0];
    float z1 = di * a1 + b3[1];
    float m = fmaxf(z0, z1);
    float lse = m + logf(expf(z0 - m) + expf(z1 - m));
    outv[node] = make_float2(z0 - lse, z1 - lse);
}

// ---------------- launch ----------------

extern "C" void kernel_launch(void* const* d_in, const int* in_sizes, int n_in,
                              void* d_out, int out_size, void* d_ws, size_t ws_size,
                              hipStream_t stream) {
    const float* x  = (const float*)d_in[0];
    const float* W1 = (const float*)d_in[1];
    const float* b1 = (const float*)d_in[2];
    const float* W2 = (const float*)d_in[3];
    const float* b2 = (const float*)d_in[4];
    const float* W3 = (const float*)d_in[5];
    const float* b3 = (const float*)d_in[6];
    const int* edges = (const int*)d_in[7];

    int n = in_sizes[0] / 9;
    int E = in_sizes[7] / 2;
    const int* src = edges;
    const int* dst = edges + E;

    char* p = (char*)d_ws;
    auto alloc = [&](size_t bytes) {
        char* q = p;
        p += (bytes + 511) & ~(size_t)511;
        return q;
    };
    int*   deg     = (int*)alloc((size_t)n * 4);
    float* dinv    = (float*)alloc((size_t)n * 4);
    int*   incl    = (int*)alloc((size_t)n * 4);
    int*   bsum    = (int*)alloc(4096);
    int*   row_ptr = (int*)alloc((size_t)(n + 1) * 4);
    int*   cursor  = (int*)alloc((size_t)n * 4);
    int2*  ew      = (int2*)alloc((size_t)E * 8);
    float* aggx    = (float*)alloc((size_t)n * 9 * 4);
    __hip_bfloat16* W2t = (__hip_bfloat16*)alloc(512 * 128 * 2);
    __hip_bfloat16* t2  = (__hip_bfloat16*)alloc((size_t)n * 128 * 2);
    float2* t3 = (float2*)alloc((size_t)n * 8);

    const int B = 256;
    hipMemsetAsync(deg, 0, (size_t)n * 4, stream);
    k_degree<<<(E + B - 1) / B, B, 0, stream>>>(dst, deg, E);
    k_dinv<<<(n + B - 1) / B, B, 0, stream>>>(deg, dinv, n);
    int nb = (n + 1023) / 1024;
    k_scan1<<<nb, 1024, 0, stream>>>(deg, incl, bsum, n);
    k_scan2<<<1, 1024, 0, stream>>>(bsum, nb);
    k_scan3<<<(n + B - 1) / B, B, 0, stream>>>(incl, deg, bsum, row_ptr, cursor, n);
    k_csr<<<(E + B - 1) / B, B, 0, stream>>>(src, dst, dinv, cursor, ew, E);

    k_agg1<<<(n + 15) / 16, B, 0, stream>>>(x, dinv, row_ptr, ew, aggx, n);
    k_w2t<<<(512 * 128 + B - 1) / B, B, 0, stream>>>(W2, W2t);
    k_l12<<<(n + 63) / 64, 256, 0, stream>>>(aggx, W1, b1, W2t, t2, n);
    k_agg2<<<(n + 3) / 4, 256, 0, stream>>>((const uint*)t2, dinv, row_ptr, ew, b2, W3, t3, n);

    k_agg3<<<(n + B - 1) / B, B, 0, stream>>>(t3, dinv, row_ptr, ew, b3, (float2*)d_out, n);
}

// Round 6
// 287.005 us; speedup vs baseline: 2.3497x; 1.0511x over previous
//
#include <hip/hip_runtime.h>
#include <hip/hip_bf16.h>

typedef __attribute__((ext_vector_type(8))) short short8;
typedef __attribute__((ext_vector_type(4))) float float4v;
typedef unsigned int uint;

static __device__ __forceinline__ float2 up_bf2(uint v) {
    float2 r;
    r.x = __uint_as_float(v << 16);
    r.y = __uint_as_float(v & 0xffff0000u);
    return r;
}
static __device__ __forceinline__ short f2bf_bits(float x) {
    union { __hip_bfloat16 h; short s; } u;
    u.h = __float2bfloat16(x);
    return u.s;
}

// ---------------- CSR build ----------------

__global__ void k_degree(const int* __restrict__ dst, int* __restrict__ deg, int E) {
    int e = blockIdx.x * blockDim.x + threadIdx.x;
    if (e < E) atomicAdd(&deg[dst[e]], 1);
}

__global__ void k_dinv(const int* __restrict__ deg, float* __restrict__ dinv, int n) {
    int i = blockIdx.x * blockDim.x + threadIdx.x;
    if (i < n) dinv[i] = rsqrtf((float)(deg[i] + 1));  // +1 self-loop; always > 0
}

__global__ void k_scan1(const int* __restrict__ deg, int* __restrict__ incl,
                        int* __restrict__ bsum, int n) {
    __shared__ int s[1024];
    int i = blockIdx.x * 1024 + threadIdx.x;
    int v = (i < n) ? deg[i] : 0;
    s[threadIdx.x] = v;
    __syncthreads();
    for (int off = 1; off < 1024; off <<= 1) {
        int t = (threadIdx.x >= off) ? s[threadIdx.x - off] : 0;
        __syncthreads();
        s[threadIdx.x] += t;
        __syncthreads();
    }
    if (i < n) incl[i] = s[threadIdx.x];
    if (threadIdx.x == 1023) bsum[blockIdx.x] = s[1023];
}

__global__ void k_scan2(int* __restrict__ bsum, int nb) {
    __shared__ int s[1024];
    int tid = threadIdx.x;
    int v = (tid < nb) ? bsum[tid] : 0;
    int orig = v;
    s[tid] = v;
    __syncthreads();
    for (int off = 1; off < 1024; off <<= 1) {
        int t = (tid >= off) ? s[tid - off] : 0;
        __syncthreads();
        s[tid] += t;
        __syncthreads();
    }
    if (tid < nb) bsum[tid] = s[tid] - orig;  // exclusive block offsets
}

__global__ void k_scan3(const int* __restrict__ incl, const int* __restrict__ deg,
                        const int* __restrict__ bofs, int* __restrict__ row_ptr,
                        int* __restrict__ cursor, int n) {
    int i = blockIdx.x * blockDim.x + threadIdx.x;
    if (i >= n) return;
    int ex = bofs[i >> 10] + incl[i] - deg[i];
    row_ptr[i] = ex;
    cursor[i] = ex;
    if (i == n - 1) row_ptr[n] = bofs[i >> 10] + incl[i];
}

// builds packed edge list: ew[pos] = {src, bits(dinv[src])}
__global__ void k_csr(const int* __restrict__ src, const int* __restrict__ dst,
                      const float* __restrict__ dinv,
                      int* __restrict__ cursor, int2* __restrict__ ew, int E) {
    int e = blockIdx.x * blockDim.x + threadIdx.x;
    if (e >= E) return;
    int s = src[e];
    int pos = atomicAdd(&cursor[dst[e]], 1);
    ew[pos] = make_int2(s, __float_as_int(dinv[s]));
}

// ---------------- Layer 1 aggregate: aggx = (D^-1/2 A D^-1/2) x ----------------

__global__ __launch_bounds__(256) void k_agg1(const float* __restrict__ x,
                       const float* __restrict__ dinv,
                       const int* __restrict__ row_ptr, const int2* __restrict__ ew,
                       float* __restrict__ aggx, int n) {
    int node = blockIdx.x * 16 + (threadIdx.x >> 4);
    if (node >= n) return;
    int f = threadIdx.x & 15;
    bool act = f < 9;
    float di = dinv[node];
    float acc = act ? di * x[node * 9 + f] : 0.f;  // self-loop
    int e0 = row_ptr[node], e1 = row_ptr[node + 1];
    int e = e0;
    for (; e + 2 <= e1; e += 2) {
        int2 wA = ew[e], wB = ew[e + 1];
        float xa = act ? x[wA.x * 9 + f] : 0.f;
        float xb = act ? x[wB.x * 9 + f] : 0.f;
        acc += __int_as_float(wA.y) * xa + __int_as_float(wB.y) * xb;
    }
    if (e < e1) {
        int2 wA = ew[e];
        float xa = act ? x[wA.x * 9 + f] : 0.f;
        acc += __int_as_float(wA.y) * xa;
    }
    if (act) aggx[node * 9 + f] = di * acc;
}

// ---------------- Layer 1 matmul: h1 = relu(aggx @ W1 + b1), bf16 ----------------
// 8 outputs per thread, short8 (16B) coalesced stores; aggx row broadcast within
// each 64-thread group.
__global__ __launch_bounds__(256) void k_l1mm(const float* __restrict__ agg,
                       const float* __restrict__ W1,
                       const float* __restrict__ b1, __hip_bfloat16* __restrict__ h1, int n) {
    int t = blockIdx.x * blockDim.x + threadIdx.x;
    if (t >= n * 64) return;
    int node = t >> 6, j0 = (t & 63) << 3;
    const float* a = agg + node * 9;
    float av[9];
#pragma unroll
    for (int f = 0; f < 9; ++f) av[f] = a[f];
    float acc[8];
#pragma unroll
    for (int j = 0; j < 8; ++j) acc[j] = b1[j0 + j];
#pragma unroll
    for (int f = 0; f < 9; ++f)
#pragma unroll
        for (int j = 0; j < 8; ++j) acc[j] += av[f] * W1[f * 512 + j0 + j];
    short8 o;
#pragma unroll
    for (int j = 0; j < 8; ++j) o[j] = f2bf_bits(fmaxf(acc[j], 0.f));
    *reinterpret_cast<short8*>(h1 + (size_t)node * 512 + j0) = o;
}

// ---------------- Layer 2 GEMM: t2 = h1 @ W2, bf16 MFMA ----------------
// Block: 256 threads (4 waves). grid = (ceil(n/256), 2).
// Stage: 64-col half of W2 (fp32->bf16) into LDS, layout [kb][col][j] (kb=k>>3):
// ds_read_b128 lane stride = 16B -> conflict-free. ONE barrier, then each wave
// streams M=64 rows x 64 cols with a 4x4 MFMA register tile, no further syncs.
__global__ __launch_bounds__(256, 2) void k_l2mm(const __hip_bfloat16* __restrict__ h1,
                       const float* __restrict__ W2,
                       __hip_bfloat16* __restrict__ t2, int n, int nchunk) {
    __shared__ short bsh[64 * 64 * 8];  // 64 KB: [kb 0..63][c 0..63][j 0..7]
    int t = threadIdx.x;
    int colbase = blockIdx.y << 6;

    // Stage B half: W2 is [512][128] fp32.
    for (int idx = t; idx < 64 * 64; idx += 256) {
        int kb = idx >> 6, c = idx & 63;
        const float* wp = W2 + (size_t)(kb * 8) * 128 + colbase + c;
        short8 o;
#pragma unroll
        for (int j = 0; j < 8; ++j) o[j] = f2bf_bits(wp[j * 128]);
        *reinterpret_cast<short8*>(bsh + (size_t)idx * 8) = o;
    }
    __syncthreads();

    int wid = t >> 6, lane = t & 63;
    int chunk = blockIdx.x * 4 + wid;
    if (chunk >= nchunk) return;
    int r = lane & 15, quad = lane >> 4;
    int m0 = chunk << 6;

    float4v acc[4][4];
#pragma unroll
    for (int mt = 0; mt < 4; ++mt)
#pragma unroll
        for (int cg = 0; cg < 4; ++cg) acc[mt][cg] = (float4v){0, 0, 0, 0};

#pragma unroll
    for (int kt = 0; kt < 16; ++kt) {
        short8 a[4], b[4];
#pragma unroll
        for (int mt = 0; mt < 4; ++mt)
            a[mt] = *reinterpret_cast<const short8*>(
                h1 + (size_t)(m0 + mt * 16 + r) * 512 + kt * 32 + quad * 8);
#pragma unroll
        for (int cg = 0; cg < 4; ++cg)
            b[cg] = *reinterpret_cast<const short8*>(
                bsh + (size_t)(((kt * 4 + quad) * 64) + cg * 16 + r) * 8);
#pragma unroll
        for (int mt = 0; mt < 4; ++mt)
#pragma unroll
            for (int cg = 0; cg < 4; ++cg)
                acc[mt][cg] = __builtin_amdgcn_mfma_f32_16x16x32_bf16(a[mt], b[cg], acc[mt][cg], 0, 0, 0);
    }

    // Epilogue: C/D col = lane&15, row = quad*4 + reg
#pragma unroll
    for (int mt = 0; mt < 4; ++mt)
#pragma unroll
        for (int i = 0; i < 4; ++i) {
            int node = m0 + mt * 16 + quad * 4 + i;
            if (node < n) {
                __hip_bfloat16* op = t2 + (size_t)node * 128 + colbase + r;
#pragma unroll
                for (int cg = 0; cg < 4; ++cg)
                    op[cg * 16] = __float2bfloat16(acc[mt][cg][i]);
            }
        }
}

// ---------------- Layer 2 aggregate + fused layer-3 matmul ----------------

__global__ __launch_bounds__(256) void k_agg2(const uint* __restrict__ t2u,
                       const float* __restrict__ dinv,
                       const int* __restrict__ row_ptr, const int2* __restrict__ ew,
                       const float* __restrict__ b2, const float* __restrict__ W3,
                       float2* __restrict__ t3, int n) {
    int node = blockIdx.x * 4 + (threadIdx.x >> 6);
    if (node >= n) return;
    int lane = threadIdx.x & 63;
    float di = dinv[node];
    float2 p = up_bf2(t2u[(size_t)node * 64 + lane]);
    float a0 = di * p.x, a1 = di * p.y;  // self-loop
    int e0 = row_ptr[node], e1 = row_ptr[node + 1];
    int e = e0;
    for (; e + 4 <= e1; e += 4) {
        int2 w0 = ew[e], w1 = ew[e + 1], w2 = ew[e + 2], w3 = ew[e + 3];
        uint r0 = t2u[(size_t)w0.x * 64 + lane];
        uint r1 = t2u[(size_t)w1.x * 64 + lane];
        uint r2 = t2u[(size_t)w2.x * 64 + lane];
        uint r3 = t2u[(size_t)w3.x * 64 + lane];
        float2 q0 = up_bf2(r0), q1 = up_bf2(r1), q2 = up_bf2(r2), q3 = up_bf2(r3);
        a0 += __int_as_float(w0.y) * q0.x + __int_as_float(w1.y) * q1.x
            + __int_as_float(w2.y) * q2.x + __int_as_float(w3.y) * q3.x;
        a1 += __int_as_float(w0.y) * q0.y + __int_as_float(w1.y) * q1.y
            + __int_as_float(w2.y) * q2.y + __int_as_float(w3.y) * q3.y;
    }
    for (; e < e1; ++e) {
        int2 w0 = ew[e];
        float2 q0 = up_bf2(t2u[(size_t)w0.x * 64 + lane]);
        a0 += __int_as_float(w0.y) * q0.x;
        a1 += __int_as_float(w0.y) * q0.y;
    }
    float2 bb = *reinterpret_cast<const float2*>(b2 + 2 * lane);
    float h0 = fmaxf(di * a0 + bb.x, 0.f);
    float h1v = fmaxf(di * a1 + bb.y, 0.f);
    float4 wv = *reinterpret_cast<const float4*>(W3 + 4 * lane);
    float c0 = h0 * wv.x + h1v * wv.z;
    float c1 = h0 * wv.y + h1v * wv.w;
#pragma unroll
    for (int off = 32; off; off >>= 1) {
        c0 += __shfl_xor(c0, off);
        c1 += __shfl_xor(c1, off);
    }
    if (lane == 0) t3[node] = make_float2(c0, c1);
}

// ---------------- Layer 3 aggregate + log_softmax ----------------

__global__ void k_agg3(const float2* __restrict__ t3, const float* __restrict__ dinv,
                       const int* __restrict__ row_ptr, const int2* __restrict__ ew,
                       const float* __restrict__ b3, float2* __restrict__ outv, int n) {
    int node = blockIdx.x * blockDim.x + threadIdx.x;
    if (node >= n) return;
    float di = dinv[node];
    float2 s = t3[node];
    float a0 = di * s.x, a1 = di * s.y;
    int e0 = row_ptr[node], e1 = row_ptr[node + 1];
    int e = e0;
    for (; e + 4 <= e1; e += 4) {
        int2 w0 = ew[e], w1 = ew[e + 1], w2 = ew[e + 2], w3 = ew[e + 3];
        float2 q0 = t3[w0.x], q1 = t3[w1.x], q2 = t3[w2.x], q3 = t3[w3.x];
        a0 += __int_as_float(w0.y) * q0.x + __int_as_float(w1.y) * q1.x
            + __int_as_float(w2.y) * q2.x + __int_as_float(w3.y) * q3.x;
        a1 += __int_as_float(w0.y) * q0.y + __int_as_float(w1.y) * q1.y
            + __int_as_float(w2.y) * q2.y + __int_as_float(w3.y) * q3.y;
    }
    for (; e < e1; ++e) {
        int2 w0 = ew[e];
        float2 q0 = t3[w0.x];
        a0 += __int_as_float(w0.y) * q0.x;
        a1 += __int_as_float(w0.y) * q0.y;
    }
    float z0 = di * a0 + b3[0];
    float z1 = di * a1 + b3[1];
    float m = fmaxf(z0, z1);
    float lse = m + logf(expf(z0 - m) + expf(z1 - m));
    outv[node] = make_float2(z0 - lse, z1 - lse);
}

// ---------------- launch ----------------

extern "C" void kernel_launch(void* const* d_in, const int* in_sizes, int n_in,
                              void* d_out, int out_size, void* d_ws, size_t ws_size,
                              hipStream_t stream) {
    const float* x  = (const float*)d_in[0];
    const float* W1 = (const float*)d_in[1];
    const float* b1 = (const float*)d_in[2];
    const float* W2 = (const float*)d_in[3];
    const float* b2 = (const float*)d_in[4];
    const float* W3 = (const float*)d_in[5];
    const float* b3 = (const float*)d_in[6];
    const int* edges = (const int*)d_in[7];

    int n = in_sizes[0] / 9;
    int E = in_sizes[7] / 2;
    const int* src = edges;
    const int* dst = edges + E;

    char* p = (char*)d_ws;
    auto alloc = [&](size_t bytes) {
        char* q = p;
        p += (bytes + 511) & ~(size_t)511;
        return q;
    };
    int npad = (n + 63) & ~63;
    int*   deg     = (int*)alloc((size_t)n * 4);
    float* dinv    = (float*)alloc((size_t)n * 4);
    int*   incl    = (int*)alloc((size_t)n * 4);
    int*   bsum    = (int*)alloc(4096);
    int*   row_ptr = (int*)alloc((size_t)(n + 1) * 4);
    int*   cursor  = (int*)alloc((size_t)n * 4);
    int2*  ew      = (int2*)alloc((size_t)E * 8);
    float* aggx    = (float*)alloc((size_t)n * 9 * 4);
    __hip_bfloat16* h1 = (__hip_bfloat16*)alloc((size_t)npad * 512 * 2);
    __hip_bfloat16* t2 = (__hip_bfloat16*)alloc((size_t)n * 128 * 2);
    float2* t3 = (float2*)alloc((size_t)n * 8);

    const int B = 256;
    hipMemsetAsync(deg, 0, (size_t)n * 4, stream);
    k_degree<<<(E + B - 1) / B, B, 0, stream>>>(dst, deg, E);
    k_dinv<<<(n + B - 1) / B, B, 0, stream>>>(deg, dinv, n);
    int nb = (n + 1023) / 1024;
    k_scan1<<<nb, 1024, 0, stream>>>(deg, incl, bsum, n);
    k_scan2<<<1, 1024, 0, stream>>>(bsum, nb);
    k_scan3<<<(n + B - 1) / B, B, 0, stream>>>(incl, deg, bsum, row_ptr, cursor, n);
    k_csr<<<(E + B - 1) / B, B, 0, stream>>>(src, dst, dinv, cursor, ew, E);

    k_agg1<<<(n + 15) / 16, B, 0, stream>>>(x, dinv, row_ptr, ew, aggx, n);
    k_l1mm<<<((size_t)n * 64 + B - 1) / B, B, 0, stream>>>(aggx, W1, b1, h1, n);

    int nchunk = (n + 63) / 64;
    dim3 g2((nchunk + 3) / 4, 2);
    k_l2mm<<<g2, 256, 0, stream>>>(h1, W2, t2, n, nchunk);
    k_agg2<<<(n + 3) / 4, 256, 0, stream>>>((const uint*)t2, dinv, row_ptr, ew, b2, W3, t3, n);

    k_agg3<<<(n + B - 1) / B, B, 0, stream>>>(t3, dinv, row_ptr, ew, b3, (float2*)d_out, n);
}